// Round 3
// baseline (300.759 us; speedup 1.0000x reference)
//
#include <hip/hip_runtime.h>
#include <math.h>

#define SEQ 4096
#define DIM 1024
#define HEADS 8
#define DINNER 512
#define QKVW 1536
#define PAD 80   // LDS row stride in bf16 elems: 160B = 10 x 16B granules, balanced banks
#define NCHUNK 4
#define CHUNK_KT 16   // 16 kt-tiles = 1024 cols per chunk

typedef unsigned short u16;
typedef __attribute__((ext_vector_type(8))) short s8v;   // 8 bf16 (4 VGPRs)
typedef __attribute__((ext_vector_type(4))) float f4v;   // 4 fp32 acc
#define MFMA(a, b, c) __builtin_amdgcn_mfma_f32_16x16x32_bf16(a, b, c, 0, 0, 0)

__device__ __forceinline__ u16 f2bf(float f) {
    unsigned u = __float_as_uint(f);
    u += 0x7fff + ((u >> 16) & 1);   // RNE
    return (u16)(u >> 16);
}
__device__ __forceinline__ float bf2f(u16 b) { return __uint_as_float(((unsigned)b) << 16); }

// ---------- RMSNorm -> split bf16 (hi, lo) ----------
__global__ __launch_bounds__(256) void rmsnorm_split(const float* __restrict__ x,
                                                     const float* __restrict__ gamma,
                                                     u16* __restrict__ hi,
                                                     u16* __restrict__ lo) {
    __shared__ float red[4];
    const int row = blockIdx.x, t = threadIdx.x;
    const float* xr = x + (size_t)row * DIM;
    float v[4];
    float ss = 0.f;
#pragma unroll
    for (int i = 0; i < 4; ++i) { v[i] = xr[t + i * 256]; ss += v[i] * v[i]; }
#pragma unroll
    for (int off = 32; off >= 1; off >>= 1) ss += __shfl_xor(ss, off, 64);
    if ((t & 63) == 0) red[t >> 6] = ss;
    __syncthreads();
    float scale = 32.0f / fmaxf(sqrtf(red[0] + red[1] + red[2] + red[3]), 1e-12f);
#pragma unroll
    for (int i = 0; i < 4; ++i) {
        int c = t + i * 256;
        float y = v[i] * scale * gamma[c];
        u16 h = f2bf(y);
        hi[(size_t)row * DIM + c] = h;
        lo[(size_t)row * DIM + c] = f2bf(y - bf2f(h));
    }
}

// ---------- transpose fp32 [R][C] -> bf16 hi/lo [C][R] ----------
__global__ __launch_bounds__(256) void transpose_split(const float* __restrict__ in,
                                                       u16* __restrict__ hi,
                                                       u16* __restrict__ lo,
                                                       int R, int C, int want_lo) {
    __shared__ float tile[64][65];
    const int c0 = blockIdx.x * 64, r0 = blockIdx.y * 64;
    const int t = threadIdx.x, col = t & 63, rb = t >> 6;
#pragma unroll
    for (int j = 0; j < 16; ++j)
        tile[rb + j * 4][col] = in[(size_t)(r0 + rb + j * 4) * C + c0 + col];
    __syncthreads();
#pragma unroll
    for (int j = 0; j < 16; ++j) {
        int cc = rb + j * 4;
        float v = tile[col][cc];
        size_t oi = (size_t)(c0 + cc) * R + r0 + col;
        u16 h = f2bf(v);
        hi[oi] = h;
        if (want_lo) lo[oi] = f2bf(v - bf2f(h));
    }
}

// ---------- QKV GEMM, split-bf16 (3 MFMAs), fused split/scale epilogue ----------
__global__ __launch_bounds__(256) void gemm_qkv_split(
    const u16* __restrict__ Ah, const u16* __restrict__ Al,
    const u16* __restrict__ Bh, const u16* __restrict__ Bl,
    u16* __restrict__ qh, u16* __restrict__ ql,
    u16* __restrict__ kh, u16* __restrict__ kl, u16* __restrict__ vtp) {
    __shared__ u16 Ash[64 * PAD], Asl[64 * PAD], Bsh[64 * PAD], Bsl[64 * PAD];
    const int t = threadIdx.x;
    const int bn = blockIdx.x * 64, bm = blockIdx.y * 64;
    const int w = t >> 6, lane = t & 63, m = lane & 15, q = lane >> 4;
    f4v acc[4] = {{0.f, 0.f, 0.f, 0.f}, {0.f, 0.f, 0.f, 0.f},
                  {0.f, 0.f, 0.f, 0.f}, {0.f, 0.f, 0.f, 0.f}};
    for (int k0 = 0; k0 < DIM; k0 += 64) {
        __syncthreads();
#pragma unroll
        for (int i = 0; i < 2; ++i) {
            int c = t + i * 256, row = c >> 3, ch = (c & 7) * 8;
            *(uint4*)&Ash[row * PAD + ch] = *(const uint4*)&Ah[(size_t)(bm + row) * DIM + k0 + ch];
            *(uint4*)&Asl[row * PAD + ch] = *(const uint4*)&Al[(size_t)(bm + row) * DIM + k0 + ch];
            *(uint4*)&Bsh[row * PAD + ch] = *(const uint4*)&Bh[(size_t)(bn + row) * DIM + k0 + ch];
            *(uint4*)&Bsl[row * PAD + ch] = *(const uint4*)&Bl[(size_t)(bn + row) * DIM + k0 + ch];
        }
        __syncthreads();
#pragma unroll
        for (int kk = 0; kk < 64; kk += 32) {
            s8v ah = *(const s8v*)&Ash[(w * 16 + m) * PAD + kk + q * 8];
            s8v al = *(const s8v*)&Asl[(w * 16 + m) * PAD + kk + q * 8];
#pragma unroll
            for (int ct = 0; ct < 4; ++ct) {
                s8v bh = *(const s8v*)&Bsh[(ct * 16 + m) * PAD + kk + q * 8];
                s8v bl = *(const s8v*)&Bsl[(ct * 16 + m) * PAD + kk + q * 8];
                acc[ct] = MFMA(ah, bh, acc[ct]);
                acc[ct] = MFMA(al, bh, acc[ct]);
                acc[ct] = MFMA(ah, bl, acc[ct]);
            }
        }
    }
    const int region = bn >> 9;   // uniform per block
#pragma unroll
    for (int ct = 0; ct < 4; ++ct) {
#pragma unroll
        for (int r = 0; r < 4; ++r) {
            int gr = bm + w * 16 + q * 4 + r;
            int gc = bn + ct * 16 + m;
            float v = acc[ct][r];
            if (region == 0) {
                v *= 8.0f;   // q * sqrt(d), faithful to reference
                u16 h = f2bf(v);
                qh[(size_t)gr * DINNER + gc] = h;
                ql[(size_t)gr * DINNER + gc] = f2bf(v - bf2f(h));
            } else if (region == 1) {
                u16 h = f2bf(v);
                kh[(size_t)gr * DINNER + (gc - 512)] = h;
                kl[(size_t)gr * DINNER + (gc - 512)] = f2bf(v - bf2f(h));
            } else {
                vtp[(size_t)(gc - 1024) * SEQ + gr] = f2bf(v);
            }
        }
    }
}

// ---------- flash attention partials: split-K chunks + register-prefetch pipeline ----------
// Block (qt, h, chunk): kt in [c*16, min(c*16+16, qt+1)). Writes unnormalized o (bf16)
// + per-row m,l. P has its own (wave-private-rows) buffer -> one less barrier, no alias.
__global__ __launch_bounds__(256) void attn_part(
    const u16* __restrict__ qh, const u16* __restrict__ ql,
    const u16* __restrict__ kh, const u16* __restrict__ kl,
    const u16* __restrict__ vt, u16* __restrict__ po,
    float* __restrict__ pm, float* __restrict__ pl) {
    __shared__ u16 Qh[64 * PAD], Ql[64 * PAD], Kh[64 * PAD], Kl[64 * PAD],
                   Vt[64 * PAD], Ps[64 * PAD];
    const int qt = blockIdx.x, h = blockIdx.y, c = blockIdx.z;
    if (qt < c * CHUNK_KT) return;   // uniform: chunk entirely above causal diagonal
    const int t = threadIdx.x;
    const int w = t >> 6, lane = t & 63, m = lane & 15, q = lane >> 4;
    const int kbeg = c * CHUNK_KT;
    const int kend = min(c * CHUNK_KT + CHUNK_KT, qt + 1);

#pragma unroll
    for (int i = 0; i < 2; ++i) {
        int cc = t + i * 256, row = cc >> 3, ch = (cc & 7) * 8;
        *(uint4*)&Qh[row * PAD + ch] =
            *(const uint4*)&qh[(size_t)(qt * 64 + row) * DINNER + h * 64 + ch];
        *(uint4*)&Ql[row * PAD + ch] =
            *(const uint4*)&ql[(size_t)(qt * 64 + row) * DINNER + h * 64 + ch];
    }

    f4v o[4] = {{0.f, 0.f, 0.f, 0.f}, {0.f, 0.f, 0.f, 0.f},
                {0.f, 0.f, 0.f, 0.f}, {0.f, 0.f, 0.f, 0.f}};
    float mi[4] = {-1e30f, -1e30f, -1e30f, -1e30f};
    float li[4] = {0.f, 0.f, 0.f, 0.f};

    // prefetch registers (2 x uint4 per array per thread)
    uint4 rkh[2], rkl[2], rv[2];
    const int cc0 = t, cc1 = t + 256;
    const int prow0 = cc0 >> 3, pch0 = (cc0 & 7) * 8;
    const int prow1 = cc1 >> 3, pch1 = (cc1 & 7) * 8;

#define ISSUE(kt_)                                                                       \
    do {                                                                                 \
        rkh[0] = *(const uint4*)&kh[(size_t)((kt_)*64 + prow0) * DINNER + h * 64 + pch0];\
        rkh[1] = *(const uint4*)&kh[(size_t)((kt_)*64 + prow1) * DINNER + h * 64 + pch1];\
        rkl[0] = *(const uint4*)&kl[(size_t)((kt_)*64 + prow0) * DINNER + h * 64 + pch0];\
        rkl[1] = *(const uint4*)&kl[(size_t)((kt_)*64 + prow1) * DINNER + h * 64 + pch1];\
        rv[0]  = *(const uint4*)&vt[(size_t)(h * 64 + prow0) * SEQ + (kt_)*64 + pch0];   \
        rv[1]  = *(const uint4*)&vt[(size_t)(h * 64 + prow1) * SEQ + (kt_)*64 + pch1];   \
    } while (0)

    ISSUE(kbeg);

    for (int kt = kbeg; kt < kend; ++kt) {
        __syncthreads();   // prior iteration done reading Kh/Kl/Vt
        *(uint4*)&Kh[prow0 * PAD + pch0] = rkh[0];
        *(uint4*)&Kh[prow1 * PAD + pch1] = rkh[1];
        *(uint4*)&Kl[prow0 * PAD + pch0] = rkl[0];
        *(uint4*)&Kl[prow1 * PAD + pch1] = rkl[1];
        *(uint4*)&Vt[prow0 * PAD + pch0] = rv[0];
        *(uint4*)&Vt[prow1 * PAD + pch1] = rv[1];
        __syncthreads();
        int ktn = (kt + 1 < kend) ? kt + 1 : kt;
        ISSUE(ktn);   // latency hides under compute below

        f4v s[4] = {{0.f, 0.f, 0.f, 0.f}, {0.f, 0.f, 0.f, 0.f},
                    {0.f, 0.f, 0.f, 0.f}, {0.f, 0.f, 0.f, 0.f}};
#pragma unroll
        for (int kk = 0; kk < 64; kk += 32) {
            s8v ah = *(const s8v*)&Qh[(w * 16 + m) * PAD + kk + q * 8];
            s8v al = *(const s8v*)&Ql[(w * 16 + m) * PAD + kk + q * 8];
#pragma unroll
            for (int ct = 0; ct < 4; ++ct) {
                s8v bh = *(const s8v*)&Kh[(ct * 16 + m) * PAD + kk + q * 8];
                s8v bl = *(const s8v*)&Kl[(ct * 16 + m) * PAD + kk + q * 8];
                s[ct] = MFMA(ah, bh, s[ct]);
                s[ct] = MFMA(al, bh, s[ct]);
                s[ct] = MFMA(ah, bl, s[ct]);
            }
        }
        if (kt == qt) {   // causal diagonal tile: mask tile-local col > row
#pragma unroll
            for (int ct = 0; ct < 4; ++ct)
#pragma unroll
                for (int r = 0; r < 4; ++r)
                    if (ct * 16 + m > w * 16 + q * 4 + r) s[ct][r] = -1e30f;
        }

        float alpha[4];
#pragma unroll
        for (int r = 0; r < 4; ++r) {
            float rm = fmaxf(fmaxf(s[0][r], s[1][r]), fmaxf(s[2][r], s[3][r]));
#pragma unroll
            for (int off = 8; off >= 1; off >>= 1) rm = fmaxf(rm, __shfl_xor(rm, off, 64));
            float mn = fmaxf(mi[r], rm);
            alpha[r] = __expf(mi[r] - mn);
            mi[r] = mn;
            float rs = 0.f;
#pragma unroll
            for (int ct = 0; ct < 4; ++ct) {
                s[ct][r] = __expf(s[ct][r] - mn);
                rs += s[ct][r];
            }
#pragma unroll
            for (int off = 8; off >= 1; off >>= 1) rs += __shfl_xor(rs, off, 64);
            li[r] = li[r] * alpha[r] + rs;
        }

        // P: wave writes and reads ONLY its own 16 rows -> no barrier needed
#pragma unroll
        for (int ct = 0; ct < 4; ++ct)
#pragma unroll
            for (int r = 0; r < 4; ++r) {
                Ps[(w * 16 + q * 4 + r) * PAD + ct * 16 + m] = f2bf(s[ct][r]);
                o[ct][r] *= alpha[r];
            }
#pragma unroll
        for (int kk = 0; kk < 64; kk += 32) {
            s8v ap = *(const s8v*)&Ps[(w * 16 + m) * PAD + kk + q * 8];
#pragma unroll
            for (int ct = 0; ct < 4; ++ct) {
                s8v bv = *(const s8v*)&Vt[(ct * 16 + m) * PAD + kk + q * 8];
                o[ct] = MFMA(ap, bv, o[ct]);
            }
        }
    }
#undef ISSUE

    // partials: po[(c,h,row)][d] bf16 (unnormalized), pm/pl[(c,h,row)]
#pragma unroll
    for (int r = 0; r < 4; ++r) {
        int grow = qt * 64 + w * 16 + q * 4 + r;
        size_t base = ((size_t)(c * HEADS + h) * SEQ + grow);
#pragma unroll
        for (int ct = 0; ct < 4; ++ct)
            po[base * 64 + ct * 16 + m] = f2bf(o[ct][r]);
        if (m == 0) { pm[base] = mi[r]; pl[base] = li[r]; }
    }
}

// ---------- merge split-K partials -> atto bf16 ----------
__global__ __launch_bounds__(256) void attn_merge(const u16* __restrict__ po,
                                                  const float* __restrict__ pm,
                                                  const float* __restrict__ pl,
                                                  u16* __restrict__ atto) {
    const int h = blockIdx.y;
    const int row = blockIdx.x * 4 + (threadIdx.x >> 6);
    const int d = threadIdx.x & 63;
    const int nc = (row >> 10) + 1;   // chunks with data for this row
    float M = -1e30f;
    for (int c = 0; c < nc; ++c)
        M = fmaxf(M, pm[(size_t)(c * HEADS + h) * SEQ + row]);
    float L = 0.f, O = 0.f;
    for (int c = 0; c < nc; ++c) {
        size_t base = (size_t)(c * HEADS + h) * SEQ + row;
        float e = __expf(pm[base] - M);
        L += pl[base] * e;
        O += bf2f(po[base * 64 + d]) * e;
    }
    atto[(size_t)row * DINNER + h * 64 + d] = f2bf(O / L);
}

// ---------- out projection: atto bf16 [4096][512] @ w_out^T bf16 [1024][512] -> fp32 ----------
__global__ __launch_bounds__(256) void gemm_out_bf16(const u16* __restrict__ A,
                                                     const u16* __restrict__ Bt,
                                                     float* __restrict__ C) {
    __shared__ u16 As[64 * PAD], Bs[64 * PAD];
    const int t = threadIdx.x;
    const int bn = blockIdx.x * 64, bm = blockIdx.y * 64;
    const int w = t >> 6, lane = t & 63, m = lane & 15, q = lane >> 4;
    f4v acc[4] = {{0.f, 0.f, 0.f, 0.f}, {0.f, 0.f, 0.f, 0.f},
                  {0.f, 0.f, 0.f, 0.f}, {0.f, 0.f, 0.f, 0.f}};
    for (int k0 = 0; k0 < DINNER; k0 += 64) {
        __syncthreads();
#pragma unroll
        for (int i = 0; i < 2; ++i) {
            int c = t + i * 256, row = c >> 3, ch = (c & 7) * 8;
            *(uint4*)&As[row * PAD + ch] = *(const uint4*)&A[(size_t)(bm + row) * DINNER + k0 + ch];
            *(uint4*)&Bs[row * PAD + ch] = *(const uint4*)&Bt[(size_t)(bn + row) * DINNER + k0 + ch];
        }
        __syncthreads();
#pragma unroll
        for (int kk = 0; kk < 64; kk += 32) {
            s8v a = *(const s8v*)&As[(w * 16 + m) * PAD + kk + q * 8];
#pragma unroll
            for (int ct = 0; ct < 4; ++ct) {
                s8v b = *(const s8v*)&Bs[(ct * 16 + m) * PAD + kk + q * 8];
                acc[ct] = MFMA(a, b, acc[ct]);
            }
        }
    }
#pragma unroll
    for (int ct = 0; ct < 4; ++ct)
#pragma unroll
        for (int r = 0; r < 4; ++r)
            C[(size_t)(bm + w * 16 + q * 4 + r) * DIM + bn + ct * 16 + m] = acc[ct][r];
}

extern "C" void kernel_launch(void* const* d_in, const int* in_sizes, int n_in,
                              void* d_out, int out_size, void* d_ws, size_t ws_size,
                              hipStream_t stream) {
    const float* x     = (const float*)d_in[0];
    const float* gamma = (const float*)d_in[1];
    const float* w_qkv = (const float*)d_in[2];
    const float* w_out = (const float*)d_in[3];
    float* out = (float*)d_out;

    // d_out overlays (all dead before their space is overwritten):
    //  phase 1: nh/nl (normed hi/lo)  -> consumed by gemm_qkv
    //  phase 2: po (attention partials, 4*8*4096*64 u16 = 16.78MB = d_out exactly)
    //           -> consumed by attn_merge, then gemm_out overwrites d_out
    u16* nh = (u16*)d_out;
    u16* nl = nh + (size_t)SEQ * DIM;
    u16* po = (u16*)d_out;

    u16* p = (u16*)d_ws;
    u16* wqt_h = p; p += (size_t)QKVW * DIM;
    u16* wqt_l = p; p += (size_t)QKVW * DIM;
    u16* wot   = p; p += (size_t)DIM * DINNER;
    u16* qh = p; p += (size_t)SEQ * DINNER;
    u16* ql = p; p += (size_t)SEQ * DINNER;
    u16* kh = p; p += (size_t)SEQ * DINNER;
    u16* kl = p; p += (size_t)SEQ * DINNER;
    u16* vt = p; p += (size_t)DINNER * SEQ;
    u16* atto = p; p += (size_t)SEQ * DINNER;
    float* pm = (float*)p; p += (size_t)2 * NCHUNK * HEADS * SEQ;
    float* pl = (float*)p; p += (size_t)2 * NCHUNK * HEADS * SEQ;

    transpose_split<<<dim3(QKVW / 64, DIM / 64), 256, 0, stream>>>(w_qkv, wqt_h, wqt_l,
                                                                   DIM, QKVW, 1);
    transpose_split<<<dim3(DIM / 64, DINNER / 64), 256, 0, stream>>>(w_out, wot, nullptr,
                                                                     DINNER, DIM, 0);
    rmsnorm_split<<<SEQ, 256, 0, stream>>>(x, gamma, nh, nl);
    gemm_qkv_split<<<dim3(QKVW / 64, SEQ / 64), 256, 0, stream>>>(nh, nl, wqt_h, wqt_l,
                                                                  qh, ql, kh, kl, vt);
    attn_part<<<dim3(SEQ / 64, HEADS, NCHUNK), 256, 0, stream>>>(qh, ql, kh, kl, vt,
                                                                 po, pm, pl);
    attn_merge<<<dim3(SEQ / 4, HEADS), 256, 0, stream>>>(po, pm, pl, atto);
    gemm_out_bf16<<<dim3(DIM / 64, SEQ / 64), 256, 0, stream>>>(atto, wot, out);
}